// Round 9
// baseline (167.114 us; speedup 1.0000x reference)
//
#include <hip/hip_runtime.h>
#include <math.h>

// CenterNetDecode fused: heat [8,80,192,192] f32, box [8,4,192,192] f32
// outputs (flat concat): boxes [B,H,W,4], mask [B,H,W], scores [B,H,W], center [B,H,W,2]
//
// Round-9 = Round-8 theory with the compile fix: __builtin_nontemporal_store
// requires native vector types, not HIP_vector_type — use ext_vector_type
// casts for the 16B/8B output stores.
//
// Structure: R6 (SS=3, 512 thr, float4/48-lane, batch->XCD swizzle) + the
// register software-pipeline RE-SIZED to fit the 128-VGPR wall.
// History: R3/R4 pipelined at SS=6 (va/vb = 64 VGPR of buffers, ~120+ live)
// -> allocator spilled everything (WRITE 191 MB, 182us). At SS=3 the same
// pipeline is va[5]+vb[5]=40 + sc=12 + prefetch 8 + addr ~25 = ~90 live,
// under the cap. R7's LDS-DMA pipeline regressed (ds_read round-trip +
// depth-1 window): REVERTED.
// Mechanism: R5/R6 showed per-wave drain-then-compute leaves VMEM idle
// (~30us vs ~18us floor) and TLP alone doesn't fix it; issuing channel
// k+1's 5 loads before computing k removes the per-channel drain.
// Outputs + box use nontemporal (no reuse; keeps XCD L2 clean for the
// vertical-halo hits the batch->XCD swizzle provides).

#define BB 8
#define CC 80
#define HH 192
#define WW 192
#define SS 3                 // rows per block strip  (HH/SS = 64 strips)
#define NPIX (SS*WW)         // 576 pixels per block
#define NBPIX (BB*HH*WW)     // 294912
#define NT 512
#define NW (NT/64)           // 8 waves
#define CPW (CC/NW)          // 10 channels per wave

typedef float vf4 __attribute__((ext_vector_type(4)));
typedef float vf2 __attribute__((ext_vector_type(2)));

__global__ __launch_bounds__(NT) void fused_kernel(const float* __restrict__ heat,
                                                   const float* __restrict__ box,
                                                   float* __restrict__ out) {
    const int tid  = threadIdx.x;
    const int lane = tid & 63;
    const int wv   = tid >> 6;        // wave 0..7
    const int bid  = blockIdx.x;      // 0..511 linear
    const int b    = bid & 7;         // XCD = bid % 8 == batch
    const int yt   = bid >> 3;        // 0..63 strip
    const int y0   = yt * SS;
    const bool lok = lane < 48;
    const int  col0 = lane * 4;

    __shared__ float red[NW][SS][WW]; // 18 KB

    float4 sc[SS];
#pragma unroll
    for (int i = 0; i < SS; ++i) sc[i] = make_float4(0.f, 0.f, 0.f, 0.f);

    const int cbase = wv * CPW;
    const float NI = -INFINITY;

    // channel load: SS+2 rows (strip + vertical halo) of float4 per lane
#define LOADCH(V, CH) {                                                        \
        const float* hp = heat + ((size_t)(b * CC + (CH)) * HH) * WW;          \
        _Pragma("unroll")                                                      \
        for (int r = 0; r < SS + 2; ++r) {                                     \
            const int  row = y0 - 1 + r;                                       \
            const bool ok  = lok && ((unsigned)row < HH);                      \
            V[r] = ok ? *reinterpret_cast<const float4*>(hp + row * WW + col0) \
                      : make_float4(NI, NI, NI, NI);                           \
        } }

    // 3x3 NMS + running channel-max into sc
#define COMPUTECH(V) {                                                         \
        _Pragma("unroll")                                                      \
        for (int i = 0; i < SS; ++i) {                                         \
            const float4 a = V[i], m = V[i + 1], d = V[i + 2];                 \
            float4 vm;                                                         \
            vm.x = fmaxf(fmaxf(a.x, m.x), d.x);                                \
            vm.y = fmaxf(fmaxf(a.y, m.y), d.y);                                \
            vm.z = fmaxf(fmaxf(a.z, m.z), d.z);                                \
            vm.w = fmaxf(fmaxf(a.w, m.w), d.w);                                \
            float L = __shfl_up(vm.w, 1);                                      \
            float R = __shfl_down(vm.x, 1);                                    \
            if (lane == 0)  L = NI;                                            \
            if (lane >= 47) R = NI;                                            \
            float4 hm;                                                         \
            hm.x = fmaxf(fmaxf(L,    vm.x), vm.y);                             \
            hm.y = fmaxf(fmaxf(vm.x, vm.y), vm.z);                             \
            hm.z = fmaxf(fmaxf(vm.y, vm.z), vm.w);                             \
            hm.w = fmaxf(fmaxf(vm.z, vm.w), R);                                \
            sc[i].x = fmaxf(sc[i].x, (m.x == hm.x) ? m.x : 0.0f);              \
            sc[i].y = fmaxf(sc[i].y, (m.y == hm.y) ? m.y : 0.0f);              \
            sc[i].z = fmaxf(sc[i].z, (m.z == hm.z) ? m.z : 0.0f);              \
            sc[i].w = fmaxf(sc[i].w, (m.w == hm.w) ? m.w : 0.0f);              \
        } }

    float4 va[SS + 2], vb[SS + 2];    // 40 VGPRs total — fits the 128 cap
    LOADCH(va, cbase);                       // prologue: channel 0 in flight
#pragma unroll
    for (int k = 0; k < CPW; k += 2) {       // CPW=10, even
        LOADCH(vb, cbase + k + 1);           // issue k+1 while k computes
        COMPUTECH(va);
        if (k + 2 < CPW) LOADCH(va, cbase + k + 2);  // issue k+2 while k+1 computes
        COMPUTECH(vb);
    }

    // ---- decode prefetch: issue box loads BEFORE the barrier (latency hides
    //      under barrier + LDS reduce). Strip is linear: pix = pixbase + idx.
    const int    pixbase = (b * HH + y0) * WW;
    const float* bp0     = box + (size_t)b * 4 * HH * WW + (size_t)y0 * WW;
    float pdx[2], pdy[2], pw[2], ph[2];
#pragma unroll
    for (int kk = 0; kk < 2; ++kk) {
        const int idx = kk * NT + tid;
        if (idx < NPIX) {
            pdx[kk] = __builtin_nontemporal_load(bp0 + idx);
            pdy[kk] = __builtin_nontemporal_load(bp0 + idx + (size_t)HH * WW);
            pw[kk]  = __builtin_nontemporal_load(bp0 + idx + (size_t)2 * HH * WW);
            ph[kk]  = __builtin_nontemporal_load(bp0 + idx + (size_t)3 * HH * WW);
        }
    }

    if (lok) {
#pragma unroll
        for (int i = 0; i < SS; ++i)
            *reinterpret_cast<float4*>(&red[wv][i][col0]) = sc[i];
    }
    __syncthreads();

    float* boxes  = out;
    float* maskp  = out + (size_t)4 * NBPIX;
    float* scorep = out + (size_t)5 * NBPIX;
    float* ctr    = out + (size_t)6 * NBPIX;

    const float* rf = &red[0][0][0];      // linear view: rf[w*NPIX + idx]

#pragma unroll
    for (int kk = 0; kk < 2; ++kk) {
        const int idx = kk * NT + tid;
        if (idx < NPIX) {
            const int row = idx / WW;
            const int x   = idx - row * WW;
            const int y   = y0 + row;

            float s = rf[idx];
#pragma unroll
            for (int w = 1; w < NW; ++w) s = fmaxf(s, rf[w * NPIX + idx]);
            const bool m = s > 0.7f;

            const float cx = ((float)x + pdx[kk]) * 4.0f;
            const float cy = ((float)y + pdy[kk]) * 4.0f;
            const float w4 = pw[kk] * 4.0f;
            const float h4 = ph[kk] * 4.0f;
            const float lim = 768.0f;
            const float x1 = fminf(fmaxf(cx - w4 * 0.5f, 0.0f), lim);
            const float y1 = fminf(fmaxf(cy - h4 * 0.5f, 0.0f), lim);
            const float x2 = fminf(fmaxf(cx + w4 * 0.5f, 0.0f), lim);
            const float y2 = fminf(fmaxf(cy + h4 * 0.5f, 0.0f), lim);

            const int pix = pixbase + idx;

            vf4 bo;
            bo.x = m ? x1 : 0.0f;
            bo.y = m ? y1 : 0.0f;
            bo.z = m ? (x2 - x1) : 0.0f;
            bo.w = m ? (y2 - y1) : 0.0f;
            __builtin_nontemporal_store(bo, reinterpret_cast<vf4*>(boxes) + pix);

            __builtin_nontemporal_store(m ? 1.0f : 0.0f, maskp + pix);
            __builtin_nontemporal_store(m ? s : 0.0f, scorep + pix);

            vf2 cc;
            cc.x = m ? cx : 0.0f;
            cc.y = m ? cy : 0.0f;
            __builtin_nontemporal_store(cc, reinterpret_cast<vf2*>(ctr) + pix);
        }
    }
}

extern "C" void kernel_launch(void* const* d_in, const int* in_sizes, int n_in,
                              void* d_out, int out_size, void* d_ws, size_t ws_size,
                              hipStream_t stream) {
    const float* heat = (const float*)d_in[0];
    const float* box  = (const float*)d_in[1];
    float* out = (float*)d_out;

    fused_kernel<<<dim3((HH / SS) * BB), NT, 0, stream>>>(heat, box, out);
}

// Round 10
// 166.235 us; speedup vs baseline: 1.0053x; 1.0053x over previous
//
#include <hip/hip_runtime.h>
#include <math.h>

// CenterNetDecode fused: heat [8,80,192,192] f32, box [8,4,192,192] f32
// outputs (flat concat): boxes [B,H,W,4], mask [B,H,W], scores [B,H,W], center [B,H,W,2]
//
// Round-10 = Round-9 + __attribute__((amdgpu_waves_per_eu(2))).
// R9 counters proved the 2-deep register pipeline spills at the default
// 128-VGPR cap (VGPR_Count=128, WRITE 53.2 MB vs 9.4 ideal, kernel 62.5us).
// LLVM's default amdgpu-waves-per-eu min=4 caps VGPRs at 512/4=128;
// __launch_bounds__ alone never moved it (R3: bare, R4: arg2=2 -> both 128).
// amdgpu_waves_per_eu(2) sets min 2 waves/EU -> cap 256. Grid = 512 blocks,
// 8 waves/block: at >128 VGPR we get 1 block/CU resident (2 waves/SIMD),
// which the pipeline is designed for: channel k+1's 5 loads are issued
// before computing k (counted vmcnt keeps them in flight), so ILP replaces
// the TLP that R5/R6 showed was insufficient anyway.
// Everything else identical to R9 (SS=3, 512 thr, float4/48-lane,
// batch->XCD swizzle, nontemporal box loads + output stores).

#define BB 8
#define CC 80
#define HH 192
#define WW 192
#define SS 3                 // rows per block strip  (HH/SS = 64 strips)
#define NPIX (SS*WW)         // 576 pixels per block
#define NBPIX (BB*HH*WW)     // 294912
#define NT 512
#define NW (NT/64)           // 8 waves
#define CPW (CC/NW)          // 10 channels per wave

typedef float vf4 __attribute__((ext_vector_type(4)));
typedef float vf2 __attribute__((ext_vector_type(2)));

__global__ __launch_bounds__(NT) __attribute__((amdgpu_waves_per_eu(2)))
void fused_kernel(const float* __restrict__ heat,
                  const float* __restrict__ box,
                  float* __restrict__ out) {
    const int tid  = threadIdx.x;
    const int lane = tid & 63;
    const int wv   = tid >> 6;        // wave 0..7
    const int bid  = blockIdx.x;      // 0..511 linear
    const int b    = bid & 7;         // XCD = bid % 8 == batch
    const int yt   = bid >> 3;        // 0..63 strip
    const int y0   = yt * SS;
    const bool lok = lane < 48;
    const int  col0 = lane * 4;

    __shared__ float red[NW][SS][WW]; // 18 KB

    float4 sc[SS];
#pragma unroll
    for (int i = 0; i < SS; ++i) sc[i] = make_float4(0.f, 0.f, 0.f, 0.f);

    const int cbase = wv * CPW;
    const float NI = -INFINITY;

    // channel load: SS+2 rows (strip + vertical halo) of float4 per lane
#define LOADCH(V, CH) {                                                        \
        const float* hp = heat + ((size_t)(b * CC + (CH)) * HH) * WW;          \
        _Pragma("unroll")                                                      \
        for (int r = 0; r < SS + 2; ++r) {                                     \
            const int  row = y0 - 1 + r;                                       \
            const bool ok  = lok && ((unsigned)row < HH);                      \
            V[r] = ok ? *reinterpret_cast<const float4*>(hp + row * WW + col0) \
                      : make_float4(NI, NI, NI, NI);                           \
        } }

    // 3x3 NMS + running channel-max into sc
#define COMPUTECH(V) {                                                         \
        _Pragma("unroll")                                                      \
        for (int i = 0; i < SS; ++i) {                                         \
            const float4 a = V[i], m = V[i + 1], d = V[i + 2];                 \
            float4 vm;                                                         \
            vm.x = fmaxf(fmaxf(a.x, m.x), d.x);                                \
            vm.y = fmaxf(fmaxf(a.y, m.y), d.y);                                \
            vm.z = fmaxf(fmaxf(a.z, m.z), d.z);                                \
            vm.w = fmaxf(fmaxf(a.w, m.w), d.w);                                \
            float L = __shfl_up(vm.w, 1);                                      \
            float R = __shfl_down(vm.x, 1);                                    \
            if (lane == 0)  L = NI;                                            \
            if (lane >= 47) R = NI;                                            \
            float4 hm;                                                         \
            hm.x = fmaxf(fmaxf(L,    vm.x), vm.y);                             \
            hm.y = fmaxf(fmaxf(vm.x, vm.y), vm.z);                             \
            hm.z = fmaxf(fmaxf(vm.y, vm.z), vm.w);                             \
            hm.w = fmaxf(fmaxf(vm.z, vm.w), R);                                \
            sc[i].x = fmaxf(sc[i].x, (m.x == hm.x) ? m.x : 0.0f);              \
            sc[i].y = fmaxf(sc[i].y, (m.y == hm.y) ? m.y : 0.0f);              \
            sc[i].z = fmaxf(sc[i].z, (m.z == hm.z) ? m.z : 0.0f);              \
            sc[i].w = fmaxf(sc[i].w, (m.w == hm.w) ? m.w : 0.0f);              \
        } }

    float4 va[SS + 2], vb[SS + 2];    // 40 VGPRs of buffers
    LOADCH(va, cbase);                       // prologue: channel 0 in flight
#pragma unroll
    for (int k = 0; k < CPW; k += 2) {       // CPW=10, even
        LOADCH(vb, cbase + k + 1);           // issue k+1 while k computes
        COMPUTECH(va);
        if (k + 2 < CPW) LOADCH(va, cbase + k + 2);  // issue k+2 while k+1 computes
        COMPUTECH(vb);
    }

    // ---- decode prefetch: issue box loads BEFORE the barrier (latency hides
    //      under barrier + LDS reduce). Strip is linear: pix = pixbase + idx.
    const int    pixbase = (b * HH + y0) * WW;
    const float* bp0     = box + (size_t)b * 4 * HH * WW + (size_t)y0 * WW;
    float pdx[2], pdy[2], pw[2], ph[2];
#pragma unroll
    for (int kk = 0; kk < 2; ++kk) {
        const int idx = kk * NT + tid;
        if (idx < NPIX) {
            pdx[kk] = __builtin_nontemporal_load(bp0 + idx);
            pdy[kk] = __builtin_nontemporal_load(bp0 + idx + (size_t)HH * WW);
            pw[kk]  = __builtin_nontemporal_load(bp0 + idx + (size_t)2 * HH * WW);
            ph[kk]  = __builtin_nontemporal_load(bp0 + idx + (size_t)3 * HH * WW);
        }
    }

    if (lok) {
#pragma unroll
        for (int i = 0; i < SS; ++i)
            *reinterpret_cast<float4*>(&red[wv][i][col0]) = sc[i];
    }
    __syncthreads();

    float* boxes  = out;
    float* maskp  = out + (size_t)4 * NBPIX;
    float* scorep = out + (size_t)5 * NBPIX;
    float* ctr    = out + (size_t)6 * NBPIX;

    const float* rf = &red[0][0][0];      // linear view: rf[w*NPIX + idx]

#pragma unroll
    for (int kk = 0; kk < 2; ++kk) {
        const int idx = kk * NT + tid;
        if (idx < NPIX) {
            const int row = idx / WW;
            const int x   = idx - row * WW;
            const int y   = y0 + row;

            float s = rf[idx];
#pragma unroll
            for (int w = 1; w < NW; ++w) s = fmaxf(s, rf[w * NPIX + idx]);
            const bool m = s > 0.7f;

            const float cx = ((float)x + pdx[kk]) * 4.0f;
            const float cy = ((float)y + pdy[kk]) * 4.0f;
            const float w4 = pw[kk] * 4.0f;
            const float h4 = ph[kk] * 4.0f;
            const float lim = 768.0f;
            const float x1 = fminf(fmaxf(cx - w4 * 0.5f, 0.0f), lim);
            const float y1 = fminf(fmaxf(cy - h4 * 0.5f, 0.0f), lim);
            const float x2 = fminf(fmaxf(cx + w4 * 0.5f, 0.0f), lim);
            const float y2 = fminf(fmaxf(cy + h4 * 0.5f, 0.0f), lim);

            const int pix = pixbase + idx;

            vf4 bo;
            bo.x = m ? x1 : 0.0f;
            bo.y = m ? y1 : 0.0f;
            bo.z = m ? (x2 - x1) : 0.0f;
            bo.w = m ? (y2 - y1) : 0.0f;
            __builtin_nontemporal_store(bo, reinterpret_cast<vf4*>(boxes) + pix);

            __builtin_nontemporal_store(m ? 1.0f : 0.0f, maskp + pix);
            __builtin_nontemporal_store(m ? s : 0.0f, scorep + pix);

            vf2 cc;
            cc.x = m ? cx : 0.0f;
            cc.y = m ? cy : 0.0f;
            __builtin_nontemporal_store(cc, reinterpret_cast<vf2*>(ctr) + pix);
        }
    }
}

extern "C" void kernel_launch(void* const* d_in, const int* in_sizes, int n_in,
                              void* d_out, int out_size, void* d_ws, size_t ws_size,
                              hipStream_t stream) {
    const float* heat = (const float*)d_in[0];
    const float* box  = (const float*)d_in[1];
    float* out = (float*)d_out;

    fused_kernel<<<dim3((HH / SS) * BB), NT, 0, stream>>>(heat, box, out);
}

// Round 11
// 145.924 us; speedup vs baseline: 1.1452x; 1.1392x over previous
//
#include <hip/hip_runtime.h>
#include <math.h>

// CenterNetDecode fused: heat [8,80,192,192] f32, box [8,4,192,192] f32
// outputs (flat concat): boxes [B,H,W,4], mask [B,H,W], scores [B,H,W], center [B,H,W,2]
//
// Round-11: 2-deep channel pipeline RESIZED TO FIT 128 VGPRs via float3/64-lane.
// Evidence trail:
//  - R6 (single-buffer float4): kernel ~40us at ~50% BW, 8% VALU, TLP-insensitive
//    -> latency-bound on the per-channel {load, drain, compute} serialization.
//  - R9 (pipeline, float4 buffers): right mechanism, but 40 regs of buffers ->
//    ~140 live vs hard 128 cap -> 10 regs/thread spilled (WRITE 53 MB, 62.5us).
//  - R10 (amdgpu_waves_per_eu(2)): cap did NOT move (VGPR=128), slower. >128 closed.
//  - THIS: float3 layout, lane l owns cols 3l..3l+2 (64x3=192 exact).
//    Buffers 40->30 regs, sc 12->9, no lane predicate (row checks are
//    wave-uniform scalar branches), all 64 lanes issue loads (+33% issue rate).
//    Live ~85 < 128 -> no spill. R2's float3 failure was the 1024-thr/64-reg
//    cap, not float3.
// Keep: SS=3, 512 thr, batch->XCD swizzle (b=bid&7), nontemporal box/output,
// bare __launch_bounds__ (no waves_per_eu).

#define BB 8
#define CC 80
#define HH 192
#define WW 192
#define SS 3                 // rows per block strip  (HH/SS = 64 strips)
#define NPIX (SS*WW)         // 576 pixels per block
#define NBPIX (BB*HH*WW)     // 294912
#define NT 512
#define NW (NT/64)           // 8 waves
#define CPW (CC/NW)          // 10 channels per wave

typedef float vf4 __attribute__((ext_vector_type(4)));
typedef float vf2 __attribute__((ext_vector_type(2)));

__global__ __launch_bounds__(NT) void fused_kernel(const float* __restrict__ heat,
                                                   const float* __restrict__ box,
                                                   float* __restrict__ out) {
    const int tid  = threadIdx.x;
    const int lane = tid & 63;
    const int wv   = tid >> 6;        // wave 0..7
    const int bid  = blockIdx.x;      // 0..511 linear
    const int b    = bid & 7;         // XCD = bid % 8 == batch
    const int yt   = bid >> 3;        // 0..63 strip
    const int y0   = yt * SS;
    const int col0 = lane * 3;        // cols 3l..3l+2, all 64 lanes active

    __shared__ float red[NW][SS][WW]; // 18 KB

    float3 sc[SS];
#pragma unroll
    for (int i = 0; i < SS; ++i) sc[i] = make_float3(0.f, 0.f, 0.f);

    const int cbase = wv * CPW;
    const float NI = -INFINITY;

    // channel load: SS+2 rows (strip + vertical halo), float3 per lane.
    // row-bound check is WAVE-UNIFORM (scalar branch, no per-lane predicate).
#define LOADCH(V, CH) {                                                        \
        const float* hp = heat + ((size_t)(b * CC + (CH)) * HH) * WW;          \
        _Pragma("unroll")                                                      \
        for (int r = 0; r < SS + 2; ++r) {                                     \
            const int row = y0 - 1 + r;                                        \
            V[r] = ((unsigned)row < HH)                                        \
                 ? *reinterpret_cast<const float3*>(hp + row * WW + col0)      \
                 : make_float3(NI, NI, NI);                                    \
        } }

    // 3x3 NMS + running channel-max into sc
#define COMPUTECH(V) {                                                         \
        _Pragma("unroll")                                                      \
        for (int i = 0; i < SS; ++i) {                                         \
            const float3 a = V[i], m = V[i + 1], d = V[i + 2];                 \
            float3 vm;                                                         \
            vm.x = fmaxf(fmaxf(a.x, m.x), d.x);                                \
            vm.y = fmaxf(fmaxf(a.y, m.y), d.y);                                \
            vm.z = fmaxf(fmaxf(a.z, m.z), d.z);                                \
            float L = __shfl_up(vm.z, 1);    /* left nb's col 3l-1  */         \
            float R = __shfl_down(vm.x, 1);  /* right nb's col 3l+3 */         \
            if (lane == 0)  L = NI;          /* image left edge  */            \
            if (lane == 63) R = NI;          /* image right edge */            \
            float3 hm;                                                         \
            hm.x = fmaxf(fmaxf(L,    vm.x), vm.y);                             \
            hm.y = fmaxf(fmaxf(vm.x, vm.y), vm.z);                             \
            hm.z = fmaxf(fmaxf(vm.y, vm.z), R);                                \
            sc[i].x = fmaxf(sc[i].x, (m.x == hm.x) ? m.x : 0.0f);              \
            sc[i].y = fmaxf(sc[i].y, (m.y == hm.y) ? m.y : 0.0f);              \
            sc[i].z = fmaxf(sc[i].z, (m.z == hm.z) ? m.z : 0.0f);              \
        } }

    float3 va[SS + 2], vb[SS + 2];    // 30 VGPRs of buffers — fits 128 cap
    LOADCH(va, cbase);                       // prologue: channel 0 in flight
#pragma unroll
    for (int k = 0; k < CPW; k += 2) {       // CPW=10, even
        LOADCH(vb, cbase + k + 1);           // issue k+1 while k computes
        COMPUTECH(va);
        if (k + 2 < CPW) LOADCH(va, cbase + k + 2);  // issue k+2 while k+1 computes
        COMPUTECH(vb);
    }

    // ---- decode prefetch: issue box loads BEFORE the barrier (latency hides
    //      under barrier + LDS reduce). Strip is linear: pix = pixbase + idx.
    const int    pixbase = (b * HH + y0) * WW;
    const float* bp0     = box + (size_t)b * 4 * HH * WW + (size_t)y0 * WW;
    float pdx[2], pdy[2], pw[2], ph[2];
#pragma unroll
    for (int kk = 0; kk < 2; ++kk) {
        const int idx = kk * NT + tid;
        if (idx < NPIX) {
            pdx[kk] = __builtin_nontemporal_load(bp0 + idx);
            pdy[kk] = __builtin_nontemporal_load(bp0 + idx + (size_t)HH * WW);
            pw[kk]  = __builtin_nontemporal_load(bp0 + idx + (size_t)2 * HH * WW);
            ph[kk]  = __builtin_nontemporal_load(bp0 + idx + (size_t)3 * HH * WW);
        }
    }

#pragma unroll
    for (int i = 0; i < SS; ++i) {
        red[wv][i][col0]     = sc[i].x;
        red[wv][i][col0 + 1] = sc[i].y;
        red[wv][i][col0 + 2] = sc[i].z;
    }
    __syncthreads();

    float* boxes  = out;
    float* maskp  = out + (size_t)4 * NBPIX;
    float* scorep = out + (size_t)5 * NBPIX;
    float* ctr    = out + (size_t)6 * NBPIX;

    const float* rf = &red[0][0][0];      // linear view: rf[w*NPIX + idx]

#pragma unroll
    for (int kk = 0; kk < 2; ++kk) {
        const int idx = kk * NT + tid;
        if (idx < NPIX) {
            const int row = idx / WW;
            const int x   = idx - row * WW;
            const int y   = y0 + row;

            float s = rf[idx];
#pragma unroll
            for (int w = 1; w < NW; ++w) s = fmaxf(s, rf[w * NPIX + idx]);
            const bool m = s > 0.7f;

            const float cx = ((float)x + pdx[kk]) * 4.0f;
            const float cy = ((float)y + pdy[kk]) * 4.0f;
            const float w4 = pw[kk] * 4.0f;
            const float h4 = ph[kk] * 4.0f;
            const float lim = 768.0f;
            const float x1 = fminf(fmaxf(cx - w4 * 0.5f, 0.0f), lim);
            const float y1 = fminf(fmaxf(cy - h4 * 0.5f, 0.0f), lim);
            const float x2 = fminf(fmaxf(cx + w4 * 0.5f, 0.0f), lim);
            const float y2 = fminf(fmaxf(cy + h4 * 0.5f, 0.0f), lim);

            const int pix = pixbase + idx;

            vf4 bo;
            bo.x = m ? x1 : 0.0f;
            bo.y = m ? y1 : 0.0f;
            bo.z = m ? (x2 - x1) : 0.0f;
            bo.w = m ? (y2 - y1) : 0.0f;
            __builtin_nontemporal_store(bo, reinterpret_cast<vf4*>(boxes) + pix);

            __builtin_nontemporal_store(m ? 1.0f : 0.0f, maskp + pix);
            __builtin_nontemporal_store(m ? s : 0.0f, scorep + pix);

            vf2 cc;
            cc.x = m ? cx : 0.0f;
            cc.y = m ? cy : 0.0f;
            __builtin_nontemporal_store(cc, reinterpret_cast<vf2*>(ctr) + pix);
        }
    }
}

extern "C" void kernel_launch(void* const* d_in, const int* in_sizes, int n_in,
                              void* d_out, int out_size, void* d_ws, size_t ws_size,
                              hipStream_t stream) {
    const float* heat = (const float*)d_in[0];
    const float* box  = (const float*)d_in[1];
    float* out = (float*)d_out;

    fused_kernel<<<dim3((HH / SS) * BB), NT, 0, stream>>>(heat, box, out);
}